// Round 6
// baseline (362.917 us; speedup 1.0000x reference)
//
#include <hip/hip_runtime.h>
#include <hip/hip_bf16.h>
#include <stdint.h>

// WindowAttention: B_=4096 windows, N=64 tokens, C=192, H=6 heads, hd=32.
// Round 6: TWO windows per block (512 thr, 8 waves; waves 0-3 window 2b,
// waves 4-7 window 2b+1) sharing one staged weight buffer. 43KB LDS ->
// 3 blocks/CU = 24 waves/CU. Per-wave algebra identical to r5 (validated).

#define NTOK 64
#define CDIM 192
#define KVROW 72          // khv row stride (shorts): 144 B

typedef __attribute__((ext_vector_type(4))) float f32x4;
typedef __attribute__((ext_vector_type(8))) short bf16x8;

__device__ __forceinline__ short f2bf(float f) {
  __hip_bfloat16 h = __float2bfloat16(f);          // RNE, hw cvt
  return *reinterpret_cast<short*>(&h);
}
__device__ __forceinline__ uint32_t pack2(float a, float b) {
  __hip_bfloat162 h2;
  h2.x = __float2bfloat16(a);
  h2.y = __float2bfloat16(b);                      // fuses to v_cvt_pk_bf16_f32
  return *reinterpret_cast<uint32_t*>(&h2);
}

// Cross-lane transpose (validated r2-r5): build bf16x8 fragment via shfl.
__device__ __forceinline__ bf16x8 xpose(uint32_t A0, uint32_t A1,
                                        uint32_t B0, uint32_t B1,
                                        int s0, int s1, int hiSel) {
  uint32_t w[4];
  uint32_t a, b;
  a = (uint32_t)__shfl((int)A0, s0); b = (uint32_t)__shfl((int)B0, s0); w[0] = hiSel ? b : a;
  a = (uint32_t)__shfl((int)A1, s0); b = (uint32_t)__shfl((int)B1, s0); w[1] = hiSel ? b : a;
  a = (uint32_t)__shfl((int)A0, s1); b = (uint32_t)__shfl((int)B0, s1); w[2] = hiSel ? b : a;
  a = (uint32_t)__shfl((int)A1, s1); b = (uint32_t)__shfl((int)B1, s1); w[3] = hiSel ? b : a;
  return *reinterpret_cast<bf16x8*>(w);
}

#define GLOAD16(g, l) __builtin_amdgcn_global_load_lds( \
    (const __attribute__((address_space(1))) void*)(g), \
    (__attribute__((address_space(3))) void*)(l), 16, 0, 0)

// Pre-convert + pre-swizzle weights into 12 chunks of 64x192 bf16.
// chunks: 0..2 Wq | 3+2p Wk-pair p | 4+2p Wv-pair p | 9..11 Wp
// Slot swizzle within chunk: s' = (s&24) | ((s^row)&7), 16B slots.
__global__ void wconv_kernel(const float* __restrict__ qkv_w,
                             const float* __restrict__ proj_w,
                             short* __restrict__ ws) {
  const int r = blockIdx.x, c = threadIdx.x;   // 768 x 192
  int chunk, lr;
  float val;
  if (r < 192)      { chunk = r >> 6;                     lr = r & 63;          val = qkv_w[r * CDIM + c]; }
  else if (r < 384) { int q = r - 192; chunk = 3 + 2 * (q >> 6); lr = q & 63;   val = qkv_w[r * CDIM + c]; }
  else if (r < 576) { int q = r - 384; chunk = 4 + 2 * (q >> 6); lr = q & 63;   val = qkv_w[r * CDIM + c]; }
  else              { int q = r - 576; chunk = 9 + (q >> 6);     lr = q & 63;   val = proj_w[q * CDIM + c]; }
  const int s = c >> 3, lo = c & 7;
  const int sp = (s & 24) | ((s ^ lr) & 7);
  ws[chunk * 12288 + lr * CDIM + sp * 8 + lo] = f2bf(val);
}

// Issue 24KB chunk with 8 waves: 3 loads per wave, wave-uniform LDS base.
__device__ __forceinline__ void stage_issue(short* __restrict__ wbuf,
                                            const short* __restrict__ src, int tid) {
  const int w = tid >> 6, lane = tid & 63;
  #pragma unroll
  for (int it = 0; it < 3; ++it) {
    const int cidx = it * 8 + w;               // wave-uniform 1KB chunk id
    GLOAD16(src + cidx * 512 + lane * 8, wbuf + cidx * 512);
  }
}

__global__ __launch_bounds__(512, 6)
void winattn_kernel(const float* __restrict__ x, const float* __restrict__ mask,
                    const short* __restrict__ ws,
                    const float* __restrict__ qkv_b, const float* __restrict__ proj_b,
                    float* __restrict__ out) {
  __shared__ __align__(16) short wbuf[64 * CDIM];      // shared weight chunk (both windows)
  __shared__ __align__(16) short khv[2][NTOK * KVROW]; // per-window K / V^T union

  const int tid  = threadIdx.x;
  const int w2   = tid >> 8;                 // which window within block
  const int b    = blockIdx.x * 2 + w2;
  const int lane = tid & 63;
  const int l16  = lane & 15;
  const int g4   = lane >> 4;
  const int m0   = ((tid >> 6) & 3) * 16;    // wave's token base within its window
  const float scale = 0.17677669529663687f;  // 32^-0.5
  const int s0 = (((2 * g4) & 3) << 4) + l16;
  const int s1 = (((2 * g4 + 1) & 3) << 4) + l16;
  const int hiSel = g4 >> 1;
  short* __restrict__ kv = khv[w2];

  // per-lane swizzled slot offsets (shorts): row&7 == l16&7 for all chunk reads
  int soff[6];
  #pragma unroll
  for (int ks = 0; ks < 6; ++ks) {
    const int s = ks * 4 + g4;
    soff[ks] = ((s & 24) | ((s ^ l16) & 7)) << 3;
  }

  // ---- prologue: kick off Wq-chunk-0 staging, then x->af ----
  stage_issue(wbuf, ws, tid);

  const float* xr = x + (size_t)b * (NTOK * CDIM) + (m0 + l16) * CDIM;
  bf16x8 af[6];
  #pragma unroll
  for (int ks = 0; ks < 6; ++ks) {
    const float4 v0 = *reinterpret_cast<const float4*>(xr + ks * 32 + g4 * 8);
    const float4 v1 = *reinterpret_cast<const float4*>(xr + ks * 32 + g4 * 8 + 4);
    uint32_t t[4];
    t[0] = pack2(v0.x, v0.y); t[1] = pack2(v0.z, v0.w);
    t[2] = pack2(v1.x, v1.y); t[3] = pack2(v1.z, v1.w);
    af[ks] = *reinterpret_cast<bf16x8*>(t);
  }
  const float* mrowl = mask + (size_t)b * (NTOK * NTOK) + (m0 + l16) * NTOK;

  __syncthreads();                             // Wq0 resident

  // ---- q phase: q^T = mfma(Wq, x) -> aq[] in registers (scale folded) ----
  bf16x8 aq[6];
  #pragma unroll
  for (int c = 0; c < 3; ++c) {
    uint32_t u[4][2];
    #pragma unroll
    for (int lct = 0; lct < 4; ++lct) {
      f32x4 acc = {0.f, 0.f, 0.f, 0.f};
      #pragma unroll
      for (int ks = 0; ks < 6; ++ks) {
        bf16x8 wf = *reinterpret_cast<const bf16x8*>(wbuf + (lct * 16 + l16) * CDIM + soff[ks]);
        acc = __builtin_amdgcn_mfma_f32_16x16x32_bf16(wf, af[ks], acc, 0, 0, 0);
      }
      const float4 bq = *reinterpret_cast<const float4*>(qkv_b + 64 * c + 16 * lct + 4 * g4);
      u[lct][0] = pack2((acc[0] + bq.x) * scale, (acc[1] + bq.y) * scale);
      u[lct][1] = pack2((acc[2] + bq.z) * scale, (acc[3] + bq.w) * scale);
    }
    __syncthreads();                           // wbuf readers done (all waves)
    stage_issue(wbuf, ws + (c < 2 ? (c + 1) : 3) * 12288, tid);  // next Wq or Wk-pair0
    aq[2 * c]     = xpose(u[0][0], u[0][1], u[1][0], u[1][1], s0, s1, hiSel);
    aq[2 * c + 1] = xpose(u[2][0], u[2][1], u[3][0], u[3][1], s0, s1, hiSel);
    __syncthreads();                           // next chunk resident
  }

  // ---- head-pair loop: p covers heads 2p, 2p+1 ----
  bf16x8 of[6];
  #pragma unroll
  for (int p = 0; p < 3; ++p) {
    // == cycle A: K-GEMM pair (wbuf = Wk rows for heads 2p,2p+1) ==
    #pragma unroll
    for (int lct = 0; lct < 4; ++lct) {
      f32x4 acc = {0.f, 0.f, 0.f, 0.f};
      #pragma unroll
      for (int ks = 0; ks < 6; ++ks) {
        bf16x8 wf = *reinterpret_cast<const bf16x8*>(wbuf + (lct * 16 + l16) * CDIM + soff[ks]);
        acc = __builtin_amdgcn_mfma_f32_16x16x32_bf16(wf, af[ks], acc, 0, 0, 0);
      }
      const float4 bk4 = *reinterpret_cast<const float4*>(qkv_b + 192 + 64 * p + 16 * lct + 4 * g4);
      uint2 kw;
      kw.x = pack2(acc[0] + bk4.x, acc[1] + bk4.y);
      kw.y = pack2(acc[2] + bk4.z, acc[3] + bk4.w);
      *reinterpret_cast<uint2*>(kv + (m0 + l16) * KVROW + 16 * lct + 4 * g4) = kw;
    }
    __syncthreads();                           // K ready; wbuf readers done
    stage_issue(wbuf, ws + (4 + 2 * p) * 12288, tid);   // Wv pair

    float4 mreg[4];
    #pragma unroll
    for (int rt = 0; rt < 4; ++rt)
      mreg[rt] = *reinterpret_cast<const float4*>(mrowl + 16 * rt + 4 * g4);

    // dual QK + softmax (two independent chains)
    bf16x8 bp[2][2];
    #pragma unroll
    for (int e = 0; e < 2; ++e) {
      float pr[4][4];
      float rmax = -1e30f;
      #pragma unroll
      for (int rt = 0; rt < 4; ++rt) {
        bf16x8 bk = *reinterpret_cast<const bf16x8*>(kv + (rt * 16 + l16) * KVROW + 32 * e + g4 * 8);
        f32x4 z = {0.f, 0.f, 0.f, 0.f};
        f32x4 s = __builtin_amdgcn_mfma_f32_16x16x32_bf16(bk, aq[2 * p + e], z, 0, 0, 0);
        pr[rt][0] = s[0] + mreg[rt].x; pr[rt][1] = s[1] + mreg[rt].y;
        pr[rt][2] = s[2] + mreg[rt].z; pr[rt][3] = s[3] + mreg[rt].w;
        #pragma unroll
        for (int i = 0; i < 4; ++i) rmax = fmaxf(rmax, pr[rt][i]);
      }
      rmax = fmaxf(rmax, __shfl_xor(rmax, 16));
      rmax = fmaxf(rmax, __shfl_xor(rmax, 32));
      float rsum = 0.f;
      #pragma unroll
      for (int rt = 0; rt < 4; ++rt)
        #pragma unroll
        for (int i = 0; i < 4; ++i) { pr[rt][i] = __expf(pr[rt][i] - rmax); rsum += pr[rt][i]; }
      rsum += __shfl_xor(rsum, 16);
      rsum += __shfl_xor(rsum, 32);
      const float rinv = 1.f / rsum;
      uint32_t wpk[4][2];
      #pragma unroll
      for (int rt = 0; rt < 4; ++rt) {
        wpk[rt][0] = pack2(pr[rt][0] * rinv, pr[rt][1] * rinv);
        wpk[rt][1] = pack2(pr[rt][2] * rinv, pr[rt][3] * rinv);
      }
      bp[e][0] = xpose(wpk[0][0], wpk[0][1], wpk[1][0], wpk[1][1], s0, s1, hiSel);
      bp[e][1] = xpose(wpk[2][0], wpk[2][1], wpk[3][0], wpk[3][1], s0, s1, hiSel);
    }
    __syncthreads();                           // Wv resident; K readers done

    // == cycle B: V-GEMM pair -> kv as V^T [ch][tok] ==
    #pragma unroll
    for (int lct = 0; lct < 4; ++lct) {
      f32x4 acc = {0.f, 0.f, 0.f, 0.f};
      #pragma unroll
      for (int ks = 0; ks < 6; ++ks) {
        bf16x8 wf = *reinterpret_cast<const bf16x8*>(wbuf + (lct * 16 + l16) * CDIM + soff[ks]);
        acc = __builtin_amdgcn_mfma_f32_16x16x32_bf16(af[ks], wf, acc, 0, 0, 0);
      }
      const float bv = qkv_b[384 + 64 * p + 16 * lct + l16];
      uint2 vw;
      vw.x = pack2(acc[0] + bv, acc[1] + bv);
      vw.y = pack2(acc[2] + bv, acc[3] + bv);
      *reinterpret_cast<uint2*>(kv + (16 * lct + l16) * KVROW + m0 + 4 * g4) = vw;
    }
    __syncthreads();                           // V^T ready; wbuf readers done
    stage_issue(wbuf, ws + (p < 2 ? (5 + 2 * p) : 9) * 12288, tid);  // next Wk-pair or Wp0

    // dual PV
    #pragma unroll
    for (int e = 0; e < 2; ++e) {
      uint32_t uo[2][2];
      #pragma unroll
      for (int ct2 = 0; ct2 < 2; ++ct2) {
        const short* vb = kv + (32 * e + 16 * ct2 + l16) * KVROW;
        bf16x8 bv1 = *reinterpret_cast<const bf16x8*>(vb + g4 * 8);
        bf16x8 bv2 = *reinterpret_cast<const bf16x8*>(vb + 32 + g4 * 8);
        f32x4 acc = {0.f, 0.f, 0.f, 0.f};
        acc = __builtin_amdgcn_mfma_f32_16x16x32_bf16(bv1, bp[e][0], acc, 0, 0, 0);
        acc = __builtin_amdgcn_mfma_f32_16x16x32_bf16(bv2, bp[e][1], acc, 0, 0, 0);
        uo[ct2][0] = pack2(acc[0], acc[1]);
        uo[ct2][1] = pack2(acc[2], acc[3]);
      }
      of[2 * p + e] = xpose(uo[0][0], uo[0][1], uo[1][0], uo[1][1], s0, s1, hiSel);
    }
    __syncthreads();                           // next wbuf resident; V readers done
  }

  // ---- proj: 3 chunks, of[] as A-operand; stores hide next-chunk latency ----
  float* og = out + (size_t)b * (NTOK * CDIM);
  #pragma unroll
  for (int c = 0; c < 3; ++c) {
    f32x4 acc[4];
    #pragma unroll
    for (int lct = 0; lct < 4; ++lct) {
      f32x4 a = {0.f, 0.f, 0.f, 0.f};
      #pragma unroll
      for (int ks = 0; ks < 6; ++ks) {
        bf16x8 wf = *reinterpret_cast<const bf16x8*>(wbuf + (lct * 16 + l16) * CDIM + soff[ks]);
        a = __builtin_amdgcn_mfma_f32_16x16x32_bf16(of[ks], wf, a, 0, 0, 0);
      }
      acc[lct] = a;
    }
    if (c < 2) {
      __syncthreads();                         // wbuf readers done
      stage_issue(wbuf, ws + (10 + c) * 12288, tid);
    }
    #pragma unroll
    for (int lct = 0; lct < 4; ++lct) {
      const int cc = 64 * c + 16 * lct + l16;
      const float pb = proj_b[cc];
      #pragma unroll
      for (int i = 0; i < 4; ++i)
        og[(m0 + 4 * g4 + i) * CDIM + cc] = acc[lct][i] + pb;
    }
    if (c < 2) __syncthreads();                // next chunk resident
  }
}

extern "C" void kernel_launch(void* const* d_in, const int* in_sizes, int n_in,
                              void* d_out, int out_size, void* d_ws, size_t ws_size,
                              hipStream_t stream) {
  const float* x      = (const float*)d_in[0];
  const float* mask   = (const float*)d_in[1];
  const float* qkv_w  = (const float*)d_in[2];
  const float* qkv_b  = (const float*)d_in[3];
  const float* proj_w = (const float*)d_in[4];
  const float* proj_b = (const float*)d_in[5];
  float* out = (float*)d_out;

  short* ws = (short*)d_ws;                    // 12 chunks x 12288 shorts = 294912 B

  wconv_kernel<<<768, 192, 0, stream>>>(qkv_w, proj_w, ws);
  winattn_kernel<<<2048, 512, 0, stream>>>(x, mask, ws, qkv_b, proj_b, out);
}

// Round 7
// 331.369 us; speedup vs baseline: 1.0952x; 1.0952x over previous
//
#include <hip/hip_runtime.h>
#include <hip/hip_bf16.h>
#include <stdint.h>

// WindowAttention: B_=4096 windows, N=64 tokens, C=192, H=6 heads, hd=32.
// Round 7: r6 structure (2 windows/block, 512 thr, shared weight staging,
// 43KB LDS -> 3 blocks/CU) with launch_bounds fixed to (512,2).
// r6's (512,6) was read as 6 BLOCKS/CU -> VGPR cap 40 -> spill disaster
// (FETCH/WRITE +860MB scratch). (512,2) restores the 128-reg budget.

#define NTOK 64
#define CDIM 192
#define KVROW 72          // khv row stride (shorts): 144 B

typedef __attribute__((ext_vector_type(4))) float f32x4;
typedef __attribute__((ext_vector_type(8))) short bf16x8;

__device__ __forceinline__ short f2bf(float f) {
  __hip_bfloat16 h = __float2bfloat16(f);          // RNE, hw cvt
  return *reinterpret_cast<short*>(&h);
}
__device__ __forceinline__ uint32_t pack2(float a, float b) {
  __hip_bfloat162 h2;
  h2.x = __float2bfloat16(a);
  h2.y = __float2bfloat16(b);                      // fuses to v_cvt_pk_bf16_f32
  return *reinterpret_cast<uint32_t*>(&h2);
}

// Cross-lane transpose (validated r2-r6): build bf16x8 fragment via shfl.
__device__ __forceinline__ bf16x8 xpose(uint32_t A0, uint32_t A1,
                                        uint32_t B0, uint32_t B1,
                                        int s0, int s1, int hiSel) {
  uint32_t w[4];
  uint32_t a, b;
  a = (uint32_t)__shfl((int)A0, s0); b = (uint32_t)__shfl((int)B0, s0); w[0] = hiSel ? b : a;
  a = (uint32_t)__shfl((int)A1, s0); b = (uint32_t)__shfl((int)B1, s0); w[1] = hiSel ? b : a;
  a = (uint32_t)__shfl((int)A0, s1); b = (uint32_t)__shfl((int)B0, s1); w[2] = hiSel ? b : a;
  a = (uint32_t)__shfl((int)A1, s1); b = (uint32_t)__shfl((int)B1, s1); w[3] = hiSel ? b : a;
  return *reinterpret_cast<bf16x8*>(w);
}

#define GLOAD16(g, l) __builtin_amdgcn_global_load_lds( \
    (const __attribute__((address_space(1))) void*)(g), \
    (__attribute__((address_space(3))) void*)(l), 16, 0, 0)

// Pre-convert + pre-swizzle weights into 12 chunks of 64x192 bf16.
// chunks: 0..2 Wq | 3+2p Wk-pair p | 4+2p Wv-pair p | 9..11 Wp
// Slot swizzle within chunk: s' = (s&24) | ((s^row)&7), 16B slots.
__global__ void wconv_kernel(const float* __restrict__ qkv_w,
                             const float* __restrict__ proj_w,
                             short* __restrict__ ws) {
  const int r = blockIdx.x, c = threadIdx.x;   // 768 x 192
  int chunk, lr;
  float val;
  if (r < 192)      { chunk = r >> 6;                     lr = r & 63;          val = qkv_w[r * CDIM + c]; }
  else if (r < 384) { int q = r - 192; chunk = 3 + 2 * (q >> 6); lr = q & 63;   val = qkv_w[r * CDIM + c]; }
  else if (r < 576) { int q = r - 384; chunk = 4 + 2 * (q >> 6); lr = q & 63;   val = qkv_w[r * CDIM + c]; }
  else              { int q = r - 576; chunk = 9 + (q >> 6);     lr = q & 63;   val = proj_w[q * CDIM + c]; }
  const int s = c >> 3, lo = c & 7;
  const int sp = (s & 24) | ((s ^ lr) & 7);
  ws[chunk * 12288 + lr * CDIM + sp * 8 + lo] = f2bf(val);
}

// Issue 24KB chunk with 8 waves: 3 loads per wave, wave-uniform LDS base.
__device__ __forceinline__ void stage_issue(short* __restrict__ wbuf,
                                            const short* __restrict__ src, int tid) {
  const int w = tid >> 6, lane = tid & 63;
  #pragma unroll
  for (int it = 0; it < 3; ++it) {
    const int cidx = it * 8 + w;               // wave-uniform 1KB chunk id
    GLOAD16(src + cidx * 512 + lane * 8, wbuf + cidx * 512);
  }
}

__global__ __launch_bounds__(512, 2)
void winattn_kernel(const float* __restrict__ x, const float* __restrict__ mask,
                    const short* __restrict__ ws,
                    const float* __restrict__ qkv_b, const float* __restrict__ proj_b,
                    float* __restrict__ out) {
  __shared__ __align__(16) short wbuf[64 * CDIM];      // shared weight chunk (both windows)
  __shared__ __align__(16) short khv[2][NTOK * KVROW]; // per-window K / V^T union

  const int tid  = threadIdx.x;
  const int w2   = tid >> 8;                 // which window within block
  const int b    = blockIdx.x * 2 + w2;
  const int lane = tid & 63;
  const int l16  = lane & 15;
  const int g4   = lane >> 4;
  const int m0   = ((tid >> 6) & 3) * 16;    // wave's token base within its window
  const float scale = 0.17677669529663687f;  // 32^-0.5
  const int s0 = (((2 * g4) & 3) << 4) + l16;
  const int s1 = (((2 * g4 + 1) & 3) << 4) + l16;
  const int hiSel = g4 >> 1;
  short* __restrict__ kv = khv[w2];

  // per-lane swizzled slot offsets (shorts): row&7 == l16&7 for all chunk reads
  int soff[6];
  #pragma unroll
  for (int ks = 0; ks < 6; ++ks) {
    const int s = ks * 4 + g4;
    soff[ks] = ((s & 24) | ((s ^ l16) & 7)) << 3;
  }

  // ---- prologue: kick off Wq-chunk-0 staging, then x->af ----
  stage_issue(wbuf, ws, tid);

  const float* xr = x + (size_t)b * (NTOK * CDIM) + (m0 + l16) * CDIM;
  bf16x8 af[6];
  #pragma unroll
  for (int ks = 0; ks < 6; ++ks) {
    const float4 v0 = *reinterpret_cast<const float4*>(xr + ks * 32 + g4 * 8);
    const float4 v1 = *reinterpret_cast<const float4*>(xr + ks * 32 + g4 * 8 + 4);
    uint32_t t[4];
    t[0] = pack2(v0.x, v0.y); t[1] = pack2(v0.z, v0.w);
    t[2] = pack2(v1.x, v1.y); t[3] = pack2(v1.z, v1.w);
    af[ks] = *reinterpret_cast<bf16x8*>(t);
  }
  const float* mrowl = mask + (size_t)b * (NTOK * NTOK) + (m0 + l16) * NTOK;

  __syncthreads();                             // Wq0 resident

  // ---- q phase: q^T = mfma(Wq, x) -> aq[] in registers (scale folded) ----
  bf16x8 aq[6];
  #pragma unroll
  for (int c = 0; c < 3; ++c) {
    uint32_t u[4][2];
    #pragma unroll
    for (int lct = 0; lct < 4; ++lct) {
      f32x4 acc = {0.f, 0.f, 0.f, 0.f};
      #pragma unroll
      for (int ks = 0; ks < 6; ++ks) {
        bf16x8 wf = *reinterpret_cast<const bf16x8*>(wbuf + (lct * 16 + l16) * CDIM + soff[ks]);
        acc = __builtin_amdgcn_mfma_f32_16x16x32_bf16(wf, af[ks], acc, 0, 0, 0);
      }
      const float4 bq = *reinterpret_cast<const float4*>(qkv_b + 64 * c + 16 * lct + 4 * g4);
      u[lct][0] = pack2((acc[0] + bq.x) * scale, (acc[1] + bq.y) * scale);
      u[lct][1] = pack2((acc[2] + bq.z) * scale, (acc[3] + bq.w) * scale);
    }
    __syncthreads();                           // wbuf readers done (all waves)
    stage_issue(wbuf, ws + (c < 2 ? (c + 1) : 3) * 12288, tid);  // next Wq or Wk-pair0
    aq[2 * c]     = xpose(u[0][0], u[0][1], u[1][0], u[1][1], s0, s1, hiSel);
    aq[2 * c + 1] = xpose(u[2][0], u[2][1], u[3][0], u[3][1], s0, s1, hiSel);
    __syncthreads();                           // next chunk resident
  }

  // ---- head-pair loop: p covers heads 2p, 2p+1 ----
  bf16x8 of[6];
  #pragma unroll
  for (int p = 0; p < 3; ++p) {
    // == cycle A: K-GEMM pair (wbuf = Wk rows for heads 2p,2p+1) ==
    #pragma unroll
    for (int lct = 0; lct < 4; ++lct) {
      f32x4 acc = {0.f, 0.f, 0.f, 0.f};
      #pragma unroll
      for (int ks = 0; ks < 6; ++ks) {
        bf16x8 wf = *reinterpret_cast<const bf16x8*>(wbuf + (lct * 16 + l16) * CDIM + soff[ks]);
        acc = __builtin_amdgcn_mfma_f32_16x16x32_bf16(wf, af[ks], acc, 0, 0, 0);
      }
      const float4 bk4 = *reinterpret_cast<const float4*>(qkv_b + 192 + 64 * p + 16 * lct + 4 * g4);
      uint2 kw;
      kw.x = pack2(acc[0] + bk4.x, acc[1] + bk4.y);
      kw.y = pack2(acc[2] + bk4.z, acc[3] + bk4.w);
      *reinterpret_cast<uint2*>(kv + (m0 + l16) * KVROW + 16 * lct + 4 * g4) = kw;
    }
    __syncthreads();                           // K ready; wbuf readers done
    stage_issue(wbuf, ws + (4 + 2 * p) * 12288, tid);   // Wv pair

    float4 mreg[4];
    #pragma unroll
    for (int rt = 0; rt < 4; ++rt)
      mreg[rt] = *reinterpret_cast<const float4*>(mrowl + 16 * rt + 4 * g4);

    // dual QK + softmax (two independent chains)
    bf16x8 bp[2][2];
    #pragma unroll
    for (int e = 0; e < 2; ++e) {
      float pr[4][4];
      float rmax = -1e30f;
      #pragma unroll
      for (int rt = 0; rt < 4; ++rt) {
        bf16x8 bk = *reinterpret_cast<const bf16x8*>(kv + (rt * 16 + l16) * KVROW + 32 * e + g4 * 8);
        f32x4 z = {0.f, 0.f, 0.f, 0.f};
        f32x4 s = __builtin_amdgcn_mfma_f32_16x16x32_bf16(bk, aq[2 * p + e], z, 0, 0, 0);
        pr[rt][0] = s[0] + mreg[rt].x; pr[rt][1] = s[1] + mreg[rt].y;
        pr[rt][2] = s[2] + mreg[rt].z; pr[rt][3] = s[3] + mreg[rt].w;
        #pragma unroll
        for (int i = 0; i < 4; ++i) rmax = fmaxf(rmax, pr[rt][i]);
      }
      rmax = fmaxf(rmax, __shfl_xor(rmax, 16));
      rmax = fmaxf(rmax, __shfl_xor(rmax, 32));
      float rsum = 0.f;
      #pragma unroll
      for (int rt = 0; rt < 4; ++rt)
        #pragma unroll
        for (int i = 0; i < 4; ++i) { pr[rt][i] = __expf(pr[rt][i] - rmax); rsum += pr[rt][i]; }
      rsum += __shfl_xor(rsum, 16);
      rsum += __shfl_xor(rsum, 32);
      const float rinv = 1.f / rsum;
      uint32_t wpk[4][2];
      #pragma unroll
      for (int rt = 0; rt < 4; ++rt) {
        wpk[rt][0] = pack2(pr[rt][0] * rinv, pr[rt][1] * rinv);
        wpk[rt][1] = pack2(pr[rt][2] * rinv, pr[rt][3] * rinv);
      }
      bp[e][0] = xpose(wpk[0][0], wpk[0][1], wpk[1][0], wpk[1][1], s0, s1, hiSel);
      bp[e][1] = xpose(wpk[2][0], wpk[2][1], wpk[3][0], wpk[3][1], s0, s1, hiSel);
    }
    __syncthreads();                           // Wv resident; K readers done

    // == cycle B: V-GEMM pair -> kv as V^T [ch][tok] ==
    #pragma unroll
    for (int lct = 0; lct < 4; ++lct) {
      f32x4 acc = {0.f, 0.f, 0.f, 0.f};
      #pragma unroll
      for (int ks = 0; ks < 6; ++ks) {
        bf16x8 wf = *reinterpret_cast<const bf16x8*>(wbuf + (lct * 16 + l16) * CDIM + soff[ks]);
        acc = __builtin_amdgcn_mfma_f32_16x16x32_bf16(af[ks], wf, acc, 0, 0, 0);
      }
      const float bv = qkv_b[384 + 64 * p + 16 * lct + l16];
      uint2 vw;
      vw.x = pack2(acc[0] + bv, acc[1] + bv);
      vw.y = pack2(acc[2] + bv, acc[3] + bv);
      *reinterpret_cast<uint2*>(kv + (16 * lct + l16) * KVROW + m0 + 4 * g4) = vw;
    }
    __syncthreads();                           // V^T ready; wbuf readers done
    stage_issue(wbuf, ws + (p < 2 ? (5 + 2 * p) : 9) * 12288, tid);  // next Wk-pair or Wp0

    // dual PV
    #pragma unroll
    for (int e = 0; e < 2; ++e) {
      uint32_t uo[2][2];
      #pragma unroll
      for (int ct2 = 0; ct2 < 2; ++ct2) {
        const short* vb = kv + (32 * e + 16 * ct2 + l16) * KVROW;
        bf16x8 bv1 = *reinterpret_cast<const bf16x8*>(vb + g4 * 8);
        bf16x8 bv2 = *reinterpret_cast<const bf16x8*>(vb + 32 + g4 * 8);
        f32x4 acc = {0.f, 0.f, 0.f, 0.f};
        acc = __builtin_amdgcn_mfma_f32_16x16x32_bf16(bv1, bp[e][0], acc, 0, 0, 0);
        acc = __builtin_amdgcn_mfma_f32_16x16x32_bf16(bv2, bp[e][1], acc, 0, 0, 0);
        uo[ct2][0] = pack2(acc[0], acc[1]);
        uo[ct2][1] = pack2(acc[2], acc[3]);
      }
      of[2 * p + e] = xpose(uo[0][0], uo[0][1], uo[1][0], uo[1][1], s0, s1, hiSel);
    }
    __syncthreads();                           // next wbuf resident; V readers done
  }

  // ---- proj: 3 chunks, of[] as A-operand; stores hide next-chunk latency ----
  float* og = out + (size_t)b * (NTOK * CDIM);
  #pragma unroll
  for (int c = 0; c < 3; ++c) {
    f32x4 acc[4];
    #pragma unroll
    for (int lct = 0; lct < 4; ++lct) {
      f32x4 a = {0.f, 0.f, 0.f, 0.f};
      #pragma unroll
      for (int ks = 0; ks < 6; ++ks) {
        bf16x8 wf = *reinterpret_cast<const bf16x8*>(wbuf + (lct * 16 + l16) * CDIM + soff[ks]);
        a = __builtin_amdgcn_mfma_f32_16x16x32_bf16(of[ks], wf, a, 0, 0, 0);
      }
      acc[lct] = a;
    }
    if (c < 2) {
      __syncthreads();                         // wbuf readers done
      stage_issue(wbuf, ws + (10 + c) * 12288, tid);
    }
    #pragma unroll
    for (int lct = 0; lct < 4; ++lct) {
      const int cc = 64 * c + 16 * lct + l16;
      const float pb = proj_b[cc];
      #pragma unroll
      for (int i = 0; i < 4; ++i)
        og[(m0 + 4 * g4 + i) * CDIM + cc] = acc[lct][i] + pb;
    }
    if (c < 2) __syncthreads();                // next chunk resident
  }
}

extern "C" void kernel_launch(void* const* d_in, const int* in_sizes, int n_in,
                              void* d_out, int out_size, void* d_ws, size_t ws_size,
                              hipStream_t stream) {
  const float* x      = (const float*)d_in[0];
  const float* mask   = (const float*)d_in[1];
  const float* qkv_w  = (const float*)d_in[2];
  const float* qkv_b  = (const float*)d_in[3];
  const float* proj_w = (const float*)d_in[4];
  const float* proj_b = (const float*)d_in[5];
  float* out = (float*)d_out;

  short* ws = (short*)d_ws;                    // 12 chunks x 12288 shorts = 294912 B

  wconv_kernel<<<768, 192, 0, stream>>>(qkv_w, proj_w, ws);
  winattn_kernel<<<2048, 512, 0, stream>>>(x, mask, ws, qkv_b, proj_b, out);
}

// Round 8
// 231.063 us; speedup vs baseline: 1.5706x; 1.4341x over previous
//
#include <hip/hip_runtime.h>
#include <hip/hip_bf16.h>
#include <stdint.h>

// WindowAttention: B_=4096 windows, N=64 tokens, C=192, H=6 heads, hd=32.
// Round 8: r4 champion structure (1 window/block, 256 thr, 4 waves) with a
// ping-pong staged weight pipeline: 24 chunks of 32x192 bf16 (12KB), two LDS
// buffers, one barrier per chunk, stage issued a FULL phase before its drain.
// Phase A(h)=K-GEMM || PV(h-1); Phase B(h)=V-GEMM || QK+softmax(h).
// LDS 38.9KB -> 4 blocks/CU. All tile algebra identical to validated r4/r7.

#define NTOK 64
#define CDIM 192
#define KROW 40           // kh row stride (shorts): 80 B
#define VROW 72           // vth row stride (shorts): 144 B

typedef __attribute__((ext_vector_type(4))) float f32x4;
typedef __attribute__((ext_vector_type(8))) short bf16x8;

__device__ __forceinline__ short f2bf(float f) {
  __hip_bfloat16 h = __float2bfloat16(f);          // RNE, hw cvt
  return *reinterpret_cast<short*>(&h);
}
__device__ __forceinline__ uint32_t pack2(float a, float b) {
  __hip_bfloat162 h2;
  h2.x = __float2bfloat16(a);
  h2.y = __float2bfloat16(b);                      // fuses to v_cvt_pk_bf16_f32
  return *reinterpret_cast<uint32_t*>(&h2);
}

// Cross-lane transpose (validated r2-r7): build bf16x8 fragment via shfl.
__device__ __forceinline__ bf16x8 xpose(uint32_t A0, uint32_t A1,
                                        uint32_t B0, uint32_t B1,
                                        int s0, int s1, int hiSel) {
  uint32_t w[4];
  uint32_t a, b;
  a = (uint32_t)__shfl((int)A0, s0); b = (uint32_t)__shfl((int)B0, s0); w[0] = hiSel ? b : a;
  a = (uint32_t)__shfl((int)A1, s0); b = (uint32_t)__shfl((int)B1, s0); w[1] = hiSel ? b : a;
  a = (uint32_t)__shfl((int)A0, s1); b = (uint32_t)__shfl((int)B0, s1); w[2] = hiSel ? b : a;
  a = (uint32_t)__shfl((int)A1, s1); b = (uint32_t)__shfl((int)B1, s1); w[3] = hiSel ? b : a;
  return *reinterpret_cast<bf16x8*>(w);
}

#define GLOAD16(g, l) __builtin_amdgcn_global_load_lds( \
    (const __attribute__((address_space(1))) void*)(g), \
    (__attribute__((address_space(3))) void*)(l), 16, 0, 0)

// Pre-convert + pre-swizzle weights into 24 chunks of 32x192 bf16.
// chunks: 0..5 Wq | 6+2h Wk_h | 7+2h Wv_h | 18..23 Wp
// Slot swizzle within chunk: s' = (s&24) | ((s^row)&7), 16B slots.
__global__ void wconv_kernel(const float* __restrict__ qkv_w,
                             const float* __restrict__ proj_w,
                             short* __restrict__ ws) {
  const int r = blockIdx.x, c = threadIdx.x;   // 768 x 192
  int chunk, lr;
  float val;
  if (r < 192)      { chunk = r >> 5;                        lr = r & 31;         val = qkv_w[r * CDIM + c]; }
  else if (r < 384) { int q = r - 192; chunk = 6 + 2 * (q >> 5); lr = q & 31;     val = qkv_w[r * CDIM + c]; }
  else if (r < 576) { int q = r - 384; chunk = 7 + 2 * (q >> 5); lr = q & 31;     val = qkv_w[r * CDIM + c]; }
  else              { int q = r - 576; chunk = 18 + (q >> 5);    lr = q & 31;     val = proj_w[q * CDIM + c]; }
  const int s = c >> 3, lo = c & 7;
  const int sp = (s & 24) | ((s ^ lr) & 7);
  ws[chunk * 6144 + lr * CDIM + sp * 8 + lo] = f2bf(val);
}

// Issue one 12KB chunk (32x192): 3 gload16 per wave, wave-uniform LDS base.
__device__ __forceinline__ void stage32(short* __restrict__ dst,
                                        const short* __restrict__ src, int tid) {
  const int w = tid >> 6, lane = tid & 63;
  #pragma unroll
  for (int it = 0; it < 3; ++it) {
    const int cidx = it * 4 + w;               // 0..11, wave-uniform
    GLOAD16(src + cidx * 512 + lane * 8, dst + cidx * 512);
  }
}

__global__ __launch_bounds__(256, 4)
void winattn_kernel(const float* __restrict__ x, const float* __restrict__ mask,
                    const short* __restrict__ ws,
                    const float* __restrict__ qkv_b, const float* __restrict__ proj_b,
                    float* __restrict__ out) {
  __shared__ __align__(16) short wbA[32 * CDIM];   // ping (even chunks)
  __shared__ __align__(16) short wbB[32 * CDIM];   // pong (odd chunks)
  __shared__ __align__(16) short kh[NTOK * KROW];  // current head k [tok][32]
  __shared__ __align__(16) short vth[2][32 * VROW];// v^T [ch][tok], head-parity dbuf

  const int b    = blockIdx.x;
  const int tid  = threadIdx.x;
  const int lane = tid & 63;
  const int l16  = lane & 15;
  const int g4   = lane >> 4;
  const int m0   = (tid >> 6) * 16;
  const float scale = 0.17677669529663687f;  // 32^-0.5
  const int s0 = (((2 * g4) & 3) << 4) + l16;
  const int s1 = (((2 * g4 + 1) & 3) << 4) + l16;
  const int hiSel = g4 >> 1;

  // per-lane swizzled slot offsets (shorts): row&7 == l16&7 for all chunk reads
  int soff[6];
  #pragma unroll
  for (int ks = 0; ks < 6; ++ks) {
    const int s = ks * 4 + g4;
    soff[ks] = ((s & 24) | ((s ^ l16) & 7)) << 3;
  }

  // ---- prologue: prime both buffers, then x->af ----
  stage32(wbA, ws, tid);                       // chunk 0
  stage32(wbB, ws + 6144, tid);                // chunk 1

  const float* xr = x + (size_t)b * (NTOK * CDIM) + (m0 + l16) * CDIM;
  bf16x8 af[6];
  #pragma unroll
  for (int ks = 0; ks < 6; ++ks) {
    const float4 v0 = *reinterpret_cast<const float4*>(xr + ks * 32 + g4 * 8);
    const float4 v1 = *reinterpret_cast<const float4*>(xr + ks * 32 + g4 * 8 + 4);
    uint32_t t[4];
    t[0] = pack2(v0.x, v0.y); t[1] = pack2(v0.z, v0.w);
    t[2] = pack2(v1.x, v1.y); t[3] = pack2(v1.z, v1.w);
    af[ks] = *reinterpret_cast<bf16x8*>(t);
  }
  const float* mrowl = mask + (size_t)b * (NTOK * NTOK) + (m0 + l16) * NTOK;

  __syncthreads();                             // chunks 0,1 resident

  // ---- Q phases: chunk c (32 q-channels) -> aq[c]; 1 barrier/chunk ----
  bf16x8 aq[6];
  #pragma unroll
  for (int c = 0; c < 6; ++c) {
    short* wb = (c & 1) ? wbB : wbA;
    uint32_t u[2][2];
    #pragma unroll
    for (int lct = 0; lct < 2; ++lct) {
      f32x4 acc = {0.f, 0.f, 0.f, 0.f};
      #pragma unroll
      for (int ks = 0; ks < 6; ++ks) {
        bf16x8 wf = *reinterpret_cast<const bf16x8*>(wb + (lct * 16 + l16) * CDIM + soff[ks]);
        acc = __builtin_amdgcn_mfma_f32_16x16x32_bf16(wf, af[ks], acc, 0, 0, 0);
      }
      const float4 bq = *reinterpret_cast<const float4*>(qkv_b + 32 * c + 16 * lct + 4 * g4);
      u[lct][0] = pack2((acc[0] + bq.x) * scale, (acc[1] + bq.y) * scale);
      u[lct][1] = pack2((acc[2] + bq.z) * scale, (acc[3] + bq.w) * scale);
    }
    aq[c] = xpose(u[0][0], u[0][1], u[1][0], u[1][1], s0, s1, hiSel);
    __syncthreads();                           // chunk c readers done; c+1 resident
    stage32(wb, ws + (c + 2) * 6144, tid);     // chunk c+2 into freed buffer
  }

  // ---- head loop: phase A (chunk 6+2h = Wk_h in wbA), phase B (7+2h = Wv_h in wbB)
  bf16x8 of[6];
  bf16x8 bpa, bpb;                             // P fragments, produced B(h), used A(h+1)
  #pragma unroll
  for (int h = 0; h < 6; ++h) {
    // == phase A(h): K-GEMM(h) || PV(h-1) ==
    #pragma unroll
    for (int lct = 0; lct < 2; ++lct) {
      f32x4 acc = {0.f, 0.f, 0.f, 0.f};
      #pragma unroll
      for (int ks = 0; ks < 6; ++ks) {
        bf16x8 wf = *reinterpret_cast<const bf16x8*>(wbA + (lct * 16 + l16) * CDIM + soff[ks]);
        acc = __builtin_amdgcn_mfma_f32_16x16x32_bf16(wf, af[ks], acc, 0, 0, 0);
      }
      const float4 bk4 = *reinterpret_cast<const float4*>(qkv_b + 192 + 32 * h + 16 * lct + 4 * g4);
      uint2 kw;
      kw.x = pack2(acc[0] + bk4.x, acc[1] + bk4.y);
      kw.y = pack2(acc[2] + bk4.z, acc[3] + bk4.w);
      *reinterpret_cast<uint2*>(kh + (m0 + l16) * KROW + 16 * lct + 4 * g4) = kw;
    }
    if (h > 0) {                               // PV(h-1) from vth[(h-1)&1]
      const int vp = (h - 1) & 1;
      uint32_t uo[2][2];
      #pragma unroll
      for (int ct2 = 0; ct2 < 2; ++ct2) {
        const short* vb = vth[vp] + (16 * ct2 + l16) * VROW;
        bf16x8 bv1 = *reinterpret_cast<const bf16x8*>(vb + g4 * 8);
        bf16x8 bv2 = *reinterpret_cast<const bf16x8*>(vb + 32 + g4 * 8);
        f32x4 acc = {0.f, 0.f, 0.f, 0.f};
        acc = __builtin_amdgcn_mfma_f32_16x16x32_bf16(bv1, bpa, acc, 0, 0, 0);
        acc = __builtin_amdgcn_mfma_f32_16x16x32_bf16(bv2, bpb, acc, 0, 0, 0);
        uo[ct2][0] = pack2(acc[0], acc[1]);
        uo[ct2][1] = pack2(acc[2], acc[3]);
      }
      of[h - 1] = xpose(uo[0][0], uo[0][1], uo[1][0], uo[1][1], s0, s1, hiSel);
    }
    __syncthreads();                           // kh visible; wbA free; Wv_h resident
    stage32(wbA, ws + (8 + 2 * h) * 6144, tid);// K_{h+1} (h<5) or proj0 (h=5)

    // == phase B(h): V-GEMM(h) || QK(h)+softmax ==
    #pragma unroll
    for (int lct = 0; lct < 2; ++lct) {
      f32x4 acc = {0.f, 0.f, 0.f, 0.f};
      #pragma unroll
      for (int ks = 0; ks < 6; ++ks) {
        bf16x8 wf = *reinterpret_cast<const bf16x8*>(wbB + (lct * 16 + l16) * CDIM + soff[ks]);
        acc = __builtin_amdgcn_mfma_f32_16x16x32_bf16(af[ks], wf, acc, 0, 0, 0);
      }
      const float bv = qkv_b[384 + 32 * h + 16 * lct + l16];
      uint2 vw;
      vw.x = pack2(acc[0] + bv, acc[1] + bv);
      vw.y = pack2(acc[2] + bv, acc[3] + bv);
      *reinterpret_cast<uint2*>(vth[h & 1] + (16 * lct + l16) * VROW + m0 + 4 * g4) = vw;
    }
    {
      float pr[4][4];
      float rmax = -1e30f;
      #pragma unroll
      for (int rt = 0; rt < 4; ++rt) {
        bf16x8 bk = *reinterpret_cast<const bf16x8*>(kh + (rt * 16 + l16) * KROW + g4 * 8);
        f32x4 z = {0.f, 0.f, 0.f, 0.f};
        f32x4 s = __builtin_amdgcn_mfma_f32_16x16x32_bf16(bk, aq[h], z, 0, 0, 0);
        const float4 mv = *reinterpret_cast<const float4*>(mrowl + 16 * rt + 4 * g4);
        pr[rt][0] = s[0] + mv.x; pr[rt][1] = s[1] + mv.y;
        pr[rt][2] = s[2] + mv.z; pr[rt][3] = s[3] + mv.w;
        #pragma unroll
        for (int i = 0; i < 4; ++i) rmax = fmaxf(rmax, pr[rt][i]);
      }
      rmax = fmaxf(rmax, __shfl_xor(rmax, 16));
      rmax = fmaxf(rmax, __shfl_xor(rmax, 32));
      float rsum = 0.f;
      #pragma unroll
      for (int rt = 0; rt < 4; ++rt)
        #pragma unroll
        for (int i = 0; i < 4; ++i) { pr[rt][i] = __expf(pr[rt][i] - rmax); rsum += pr[rt][i]; }
      rsum += __shfl_xor(rsum, 16);
      rsum += __shfl_xor(rsum, 32);
      const float rinv = 1.f / rsum;
      uint32_t wpk[4][2];
      #pragma unroll
      for (int rt = 0; rt < 4; ++rt) {
        wpk[rt][0] = pack2(pr[rt][0] * rinv, pr[rt][1] * rinv);
        wpk[rt][1] = pack2(pr[rt][2] * rinv, pr[rt][3] * rinv);
      }
      bpa = xpose(wpk[0][0], wpk[0][1], wpk[1][0], wpk[1][1], s0, s1, hiSel);
      bpb = xpose(wpk[2][0], wpk[2][1], wpk[3][0], wpk[3][1], s0, s1, hiSel);
    }
    __syncthreads();                           // vth visible; wbB free; next chunk resident
    stage32(wbB, ws + (9 + 2 * h) * 6144, tid);// V_{h+1} (h<5) or proj1 (h=5)
  }

  // ---- proj phases: chunks 18..23 (32 out-cols each); PV(5) folded into first ----
  float* og = out + (size_t)b * (NTOK * CDIM);
  #pragma unroll
  for (int j = 0; j < 6; ++j) {
    const int c = 18 + j;
    short* wb = (c & 1) ? wbB : wbA;
    if (j == 0) {                              // PV(5) -> of[5]
      uint32_t uo[2][2];
      #pragma unroll
      for (int ct2 = 0; ct2 < 2; ++ct2) {
        const short* vb = vth[1] + (16 * ct2 + l16) * VROW;
        bf16x8 bv1 = *reinterpret_cast<const bf16x8*>(vb + g4 * 8);
        bf16x8 bv2 = *reinterpret_cast<const bf16x8*>(vb + 32 + g4 * 8);
        f32x4 acc = {0.f, 0.f, 0.f, 0.f};
        acc = __builtin_amdgcn_mfma_f32_16x16x32_bf16(bv1, bpa, acc, 0, 0, 0);
        acc = __builtin_amdgcn_mfma_f32_16x16x32_bf16(bv2, bpb, acc, 0, 0, 0);
        uo[ct2][0] = pack2(acc[0], acc[1]);
        uo[ct2][1] = pack2(acc[2], acc[3]);
      }
      of[5] = xpose(uo[0][0], uo[0][1], uo[1][0], uo[1][1], s0, s1, hiSel);
    }
    #pragma unroll
    for (int lct = 0; lct < 2; ++lct) {
      f32x4 acc = {0.f, 0.f, 0.f, 0.f};
      #pragma unroll
      for (int ks = 0; ks < 6; ++ks) {
        bf16x8 wf = *reinterpret_cast<const bf16x8*>(wb + (lct * 16 + l16) * CDIM + soff[ks]);
        acc = __builtin_amdgcn_mfma_f32_16x16x32_bf16(of[ks], wf, acc, 0, 0, 0);
      }
      const int cc = 32 * j + 16 * lct + l16;
      const float pb = proj_b[cc];
      #pragma unroll
      for (int i = 0; i < 4; ++i)
        og[(m0 + 4 * g4 + i) * CDIM + cc] = acc[i] + pb;
    }
    if (j < 5) {
      __syncthreads();                         // chunk c readers done; c+1 resident
      if (j < 4) stage32(wb, ws + (c + 2) * 6144, tid);
    }
  }
}

extern "C" void kernel_launch(void* const* d_in, const int* in_sizes, int n_in,
                              void* d_out, int out_size, void* d_ws, size_t ws_size,
                              hipStream_t stream) {
  const float* x      = (const float*)d_in[0];
  const float* mask   = (const float*)d_in[1];
  const float* qkv_w  = (const float*)d_in[2];
  const float* qkv_b  = (const float*)d_in[3];
  const float* proj_w = (const float*)d_in[4];
  const float* proj_b = (const float*)d_in[5];
  float* out = (float*)d_out;

  short* ws = (short*)d_ws;                    // 24 chunks x 6144 shorts = 294912 B

  wconv_kernel<<<768, 192, 0, stream>>>(qkv_w, proj_w, ws);
  winattn_kernel<<<4096, 256, 0, stream>>>(x, mask, ws, qkv_b, proj_b, out);
}